// Round 13
// baseline (83.018 us; speedup 1.0000x reference)
//
#include <hip/hip_runtime.h>
#include <hip/hip_bf16.h>
#include <math.h>

#define BATCH 4
#define SEQ   2048
#define DIM   1024
#define HEAD  64
#define NCHUNK ((BATCH * SEQ * SEQ) / 64)   // 262144 64-bool chunks

typedef __attribute__((ext_vector_type(8))) short bf16x8;
typedef __attribute__((ext_vector_type(4))) short bf16x4;
typedef __attribute__((ext_vector_type(4))) float f32x4;

static __device__ __forceinline__ short f2bf(float f) {
    __hip_bfloat16 h = __float2bfloat16(f);     // RNE
    return *reinterpret_cast<short*>(&h);
}

// ---------------------------------------------------------------------------
// Prelude: W[1024][64] f32 -> frag-major Wt2[which][k/32][64][32] bf16, so a
// proj wave's B-frag load (n,c,g lanes) is one contiguous 1KB segment.
// Plus mask dtype detect (int32 bools are {0,1}; byte-bools read as u32
// exceed 1 w.p. 7/8 per word).
// ---------------------------------------------------------------------------
__global__ __launch_bounds__(256) void wconv_detect_kernel(
    const float* __restrict__ Wq, const float* __restrict__ Wk, const float* __restrict__ Wv,
    short* __restrict__ Wt, const unsigned int* __restrict__ mask_u32,
    int* __restrict__ mflag)
{
    const int which = blockIdx.y;
    const float* __restrict__ W = (which == 0) ? Wq : (which == 1) ? Wk : Wv;
    short* __restrict__ Wtw = Wt + (size_t)which * HEAD * DIM;

    const int h  = threadIdx.x & 63;
    const int k0 = blockIdx.x * 64 + (threadIdx.x >> 6) * 16;
    #pragma unroll
    for (int j = 0; j < 16; ++j) {
        int k = k0 + j;
        Wtw[((size_t)(k >> 5) * 64 + h) * 32 + (k & 31)] =
            f2bf(W[(size_t)k * HEAD + h]);
    }

    if (blockIdx.x == 0 && blockIdx.y == 0 && threadIdx.x < 64) {
        int lane = threadIdx.x;
        bool weird = false;
        for (int i = lane; i < 1024; i += 64) weird |= (mask_u32[i] > 1u);
        unsigned long long b = __ballot(weird);
        if (lane == 0) *mflag = (b != 0ull) ? 1 : 0;
    }
}

// ---------------------------------------------------------------------------
// Projection v9: X[8192,1024]f32 @ W -> bf16 Q/K/Vt.
// proj5 structure (1536 blocks x 256 thr; 16 rows x 64 cols; 4 waves split-K
// 256 each; 16 KB LDS f32 merge) + the missing piece: a KEEP-ALIVE ASM FENCE.
// All 24 loads of a half-chunk (8 X f32x4 + 16 W bf16x8) are read+written by
// one volatile asm as "+v" operands -> true SSA dependency: the compiler must
// issue all 24 loads before one combined s_waitcnt and hold ~96 VGPRs live.
// (R9's sched_barrier(0) had no dataflow and was ignored: VGPR stayed 60.
//  R12's fusion test proved the stall is per-CU outstanding-load starvation:
//  pack waves sharing the CU time-shared instead of filling idle slots.)
// ---------------------------------------------------------------------------
__global__ __launch_bounds__(256, 3) void proj9_kernel(
    const float* __restrict__ Xq, const float* __restrict__ Xk, const float* __restrict__ Xv,
    const short* __restrict__ Wt,
    short* __restrict__ Q, short* __restrict__ K, short* __restrict__ Vt)
{
    const int which = blockIdx.x >> 9;          // 0:Q 1:K 2:V
    const int row0  = (blockIdx.x & 511) * 16;  // global row (b*S+s)
    const float* __restrict__ X = (which == 0) ? Xq : (which == 1) ? Xk : Xv;
    const short* __restrict__ Wtw = Wt + (size_t)which * HEAD * DIM;

    const int tid  = threadIdx.x;
    const int lane = tid & 63;
    const int w    = tid >> 6;                  // wave = K-chunk of 256
    const int g    = lane >> 4;
    const int c    = lane & 15;

    __shared__ float O_lds[4][16][64];          // [wave][row][col] partials

    const float* __restrict__ Xp = X + (size_t)(row0 + c) * DIM + w * 256 + g * 8;
    // frag-major W: chunk (w*8 + half*4 + s), lane offset (n*16+c)*32 + g*8
    const short* __restrict__ Wp = Wtw + (size_t)(w * 8) * 2048 + c * 32 + g * 8;

    f32x4 acc[4];
    #pragma unroll
    for (int n = 0; n < 4; ++n) acc[n] = (f32x4)0.0f;

    #pragma unroll
    for (int half = 0; half < 2; ++half) {
        // --- all X loads for this half (8 independent 16B) ---
        f32x4 xa0 = *(const f32x4*)(Xp + half * 128 + 0 * 32);
        f32x4 xb0 = *(const f32x4*)(Xp + half * 128 + 0 * 32 + 4);
        f32x4 xa1 = *(const f32x4*)(Xp + half * 128 + 1 * 32);
        f32x4 xb1 = *(const f32x4*)(Xp + half * 128 + 1 * 32 + 4);
        f32x4 xa2 = *(const f32x4*)(Xp + half * 128 + 2 * 32);
        f32x4 xb2 = *(const f32x4*)(Xp + half * 128 + 2 * 32 + 4);
        f32x4 xa3 = *(const f32x4*)(Xp + half * 128 + 3 * 32);
        f32x4 xb3 = *(const f32x4*)(Xp + half * 128 + 3 * 32 + 4);
        // --- all W frag loads for this half (16 independent 16B) ---
        bf16x8 wf[16];
        #pragma unroll
        for (int s = 0; s < 4; ++s)
            #pragma unroll
            for (int n = 0; n < 4; ++n)
                wf[s * 4 + n] = *(const bf16x8*)(Wp + (size_t)(half * 4 + s) * 2048
                                                 + n * 512);
        // KEEP-ALIVE FENCE: asm reads+writes all 24 results. Compiler must
        // issue every load above this point (one combined waitcnt) and keep
        // all ~96 VGPRs live. Two statements to stay under operand limits.
        asm volatile("" : "+v"(xa0), "+v"(xb0), "+v"(xa1), "+v"(xb1),
                          "+v"(xa2), "+v"(xb2), "+v"(xa3), "+v"(xb3));
        asm volatile("" : "+v"(wf[0]), "+v"(wf[1]), "+v"(wf[2]), "+v"(wf[3]),
                          "+v"(wf[4]), "+v"(wf[5]), "+v"(wf[6]), "+v"(wf[7]),
                          "+v"(wf[8]), "+v"(wf[9]), "+v"(wf[10]), "+v"(wf[11]),
                          "+v"(wf[12]), "+v"(wf[13]), "+v"(wf[14]), "+v"(wf[15]));
        __builtin_amdgcn_sched_barrier(0);
        // --- compute ---
        f32x4 xs[8] = {xa0, xb0, xa1, xb1, xa2, xb2, xa3, xb3};
        #pragma unroll
        for (int s = 0; s < 4; ++s) {
            bf16x8 a;
            a[0]=f2bf(xs[s*2][0]); a[1]=f2bf(xs[s*2][1]);
            a[2]=f2bf(xs[s*2][2]); a[3]=f2bf(xs[s*2][3]);
            a[4]=f2bf(xs[s*2+1][0]); a[5]=f2bf(xs[s*2+1][1]);
            a[6]=f2bf(xs[s*2+1][2]); a[7]=f2bf(xs[s*2+1][3]);
            #pragma unroll
            for (int n = 0; n < 4; ++n)
                acc[n] = __builtin_amdgcn_mfma_f32_16x16x32_bf16(a, wf[s * 4 + n],
                                                                 acc[n], 0, 0, 0);
        }
    }

    // publish partials: C/D layout col = lane&15 (W col), row = g*4+reg (X row)
    #pragma unroll
    for (int n = 0; n < 4; ++n)
        #pragma unroll
        for (int r = 0; r < 4; ++r)
            O_lds[w][g * 4 + r][n * 16 + c] = acc[n][r];
    __syncthreads();

    if (which < 2) {
        short* dst = (which == 0) ? Q : K;
        const int trow = tid >> 4, c4 = (tid & 15) * 4;
        f32x4 sum = *(const f32x4*)&O_lds[0][trow][c4];
        #pragma unroll
        for (int i = 1; i < 4; ++i) {
            f32x4 t = *(const f32x4*)&O_lds[i][trow][c4];
            sum[0] += t[0]; sum[1] += t[1]; sum[2] += t[2]; sum[3] += t[3];
        }
        bf16x4 pk;
        #pragma unroll
        for (int j = 0; j < 4; ++j) pk[j] = f2bf(sum[j]);
        *(bf16x4*)&dst[(size_t)(row0 + trow) * HEAD + c4] = pk;
    } else {
        // Vt[b][h][s]: thread owns one h, 4 consecutive s
        const int h = tid & 63, r4 = (tid >> 6) * 4;
        const int b = row0 >> 11, sb = row0 & (SEQ - 1);
        bf16x4 pk;
        #pragma unroll
        for (int j = 0; j < 4; ++j) {
            float v = O_lds[0][r4 + j][h] + O_lds[1][r4 + j][h]
                    + O_lds[2][r4 + j][h] + O_lds[3][r4 + j][h];
            pk[j] = f2bf(v);
        }
        *(bf16x4*)&Vt[((size_t)(b * HEAD + h)) * SEQ + sb + r4] = pk;
    }
}

// ---------------------------------------------------------------------------
// Mask bit-pack: 16 independent 256B loads in flight per wave,
// 512 blocks x 4 waves; wave owns 128 consecutive chunks. (6.1 TB/s, at floor)
// ---------------------------------------------------------------------------
__global__ __launch_bounds__(256) void pack_kernel(
    const void* __restrict__ mask, const int* __restrict__ mflag,
    unsigned long long* __restrict__ packed)
{
    const int lane = threadIdx.x & 63;
    const int gw   = blockIdx.x * 4 + (threadIdx.x >> 6);   // 0..2047
    const int c0   = gw * 128;
    const int useByte = *mflag;
    if (useByte) {
        const unsigned char* mb = (const unsigned char*)mask;
        for (int i = 0; i < 8; ++i) {
            unsigned char v[16];
            #pragma unroll
            for (int j = 0; j < 16; ++j)
                v[j] = mb[(size_t)(c0 + i * 16 + j) * 64 + lane];
            #pragma unroll
            for (int j = 0; j < 16; ++j) {
                unsigned long long bb = __ballot(v[j] != 0);
                if (lane == 0) packed[c0 + i * 16 + j] = bb;
            }
        }
    } else {
        const unsigned int* mw = (const unsigned int*)mask;
        for (int i = 0; i < 8; ++i) {
            unsigned int v[16];
            #pragma unroll
            for (int j = 0; j < 16; ++j)
                v[j] = mw[(size_t)(c0 + i * 16 + j) * 64 + lane];
            #pragma unroll
            for (int j = 0; j < 16; ++j) {
                unsigned long long bb = __ballot(v[j] != 0);
                if (lane == 0) packed[c0 + i * 16 + j] = bb;
            }
        }
    }
}

// ---------------------------------------------------------------------------
// Flash attention: grid (S/16, B), 512 threads = 8 waves; wave w owns keys
// [w*256,(w+1)*256). Swapped QK^T (S^T = mfma(K,Q)) puts a full q-row in-lane:
// softmax reduce = in-lane tree + 2 shfl_xor. Mask preloaded as 8 bit-words
// per lane. Defer-max rescale (THR=8). P->LDS transpose -> PV MFMA.
// ---------------------------------------------------------------------------
__global__ __launch_bounds__(512, 4) void attn_kernel(
    const short* __restrict__ Q, const short* __restrict__ K, const short* __restrict__ Vt,
    const unsigned int* __restrict__ packed, float* __restrict__ out)
{
    const int qbase = blockIdx.x * 16;
    const int b     = blockIdx.y;
    const int tid  = threadIdx.x;
    const int lane = tid & 63;
    const int w    = tid >> 6;          // wave 0..7 = key segment
    const int g    = lane >> 4;
    const int c    = lane & 15;

    const short* Qb = Q  + (size_t)(b * SEQ + qbase) * HEAD;
    const short* Kb = K  + (size_t)b * SEQ * HEAD;
    const short* Vb = Vt + (size_t)b * HEAD * SEQ;

    // LDS: P (loop phase, 8KB) aliases O (merge phase, 32KB); M/L after.
    __shared__ __align__(16) unsigned char smem[32768 + 1024];
    short (*P_lds)[4][16][8] = (short (*)[4][16][8])smem;   // [wave][kgrp][q][8]
    float (*O_lds)[16][64]   = (float (*)[16][64])smem;     // [wave][q][h]
    float (*M_lds)[16] = (float (*)[16])(smem + 32768);     // [wave][q]
    float (*L_lds)[16] = (float (*)[16])(smem + 32768 + 512);

    // per-lane mask bits for q = qbase+c, keys w*256..w*256+255 (8 u32 words)
    const unsigned int* pw = packed + (size_t)(b * SEQ + qbase + c) * 64 + w * 8;
    unsigned int mwords[8];
    #pragma unroll
    for (int i = 0; i < 8; ++i) mwords[i] = pw[i];

    // Q as B-operand fragments (col q = c, k = head dim)
    bf16x8 qb0 = *(const bf16x8*)&Qb[c * HEAD + g * 8];
    bf16x8 qb1 = *(const bf16x8*)&Qb[c * HEAD + 32 + g * 8];

    float m_run = -INFINITY, l_run = 0.0f;
    f32x4 o[4];
    #pragma unroll
    for (int n = 0; n < 4; ++n) o[n] = (f32x4)0.0f;

    const float scale = 0.125f;                    // HEAD^-0.5
    const float LOG2E = 1.44269504088896340736f;

    for (int i = 0; i < 8; ++i) {
        const int kt = w * 8 + i;                  // key tile of 32
        const short* Kt = Kb + (size_t)kt * 32 * HEAD;

        // V^T B-fragments (issued early, independent of QK chain)
        bf16x8 vb[4];
        #pragma unroll
        for (int n = 0; n < 4; ++n)
            vb[n] = *(const bf16x8*)&Vb[(size_t)(n * 16 + c) * SEQ + kt * 32 + g * 8];

        // K as A-operand (row = key = c / 16+c, k = head dim)
        bf16x8 ka00 = *(const bf16x8*)&Kt[c * HEAD + g * 8];
        bf16x8 ka01 = *(const bf16x8*)&Kt[c * HEAD + 32 + g * 8];
        bf16x8 ka10 = *(const bf16x8*)&Kt[(16 + c) * HEAD + g * 8];
        bf16x8 ka11 = *(const bf16x8*)&Kt[(16 + c) * HEAD + 32 + g * 8];

        // S^T tiles: lane holds q=c, keys g*4+r (s0) and 16+g*4+r (s1)
        f32x4 s0 = (f32x4)0.0f, s1 = (f32x4)0.0f;
        s0 = __builtin_amdgcn_mfma_f32_16x16x32_bf16(ka00, qb0, s0, 0, 0, 0);
        s0 = __builtin_amdgcn_mfma_f32_16x16x32_bf16(ka01, qb1, s0, 0, 0, 0);
        s1 = __builtin_amdgcn_mfma_f32_16x16x32_bf16(ka10, qb0, s1, 0, 0, 0);
        s1 = __builtin_amdgcn_mfma_f32_16x16x32_bf16(ka11, qb1, s1, 0, 0, 0);

        // scale + mask from preloaded bits (bit j of word = key kt*32+j)
        const unsigned int mw32 = mwords[i];
        float sv[8];
        #pragma unroll
        for (int r = 0; r < 4; ++r) {
            sv[r]     = ((mw32 >> (g * 4 + r)) & 1u)      ? -INFINITY : s0[r] * scale;
            sv[4 + r] = ((mw32 >> (16 + g * 4 + r)) & 1u) ? -INFINITY : s1[r] * scale;
        }

        // row max: in-lane tree + cross-group (lanes c, c+16, c+32, c+48)
        float mx = fmaxf(fmaxf(fmaxf(sv[0], sv[1]), fmaxf(sv[2], sv[3])),
                         fmaxf(fmaxf(sv[4], sv[5]), fmaxf(sv[6], sv[7])));
        mx = fmaxf(mx, __shfl_xor(mx, 16));
        mx = fmaxf(mx, __shfl_xor(mx, 32));

        // defer-max: rescale only when max grows past threshold (rare)
        if (!__all(mx <= m_run + 8.0f)) {
            float mn = fmaxf(m_run, mx);
            float cf = (m_run == mn) ? 1.0f : exp2f((m_run - mn) * LOG2E);
            float cfq[4];
            #pragma unroll
            for (int r = 0; r < 4; ++r)
                cfq[r] = __shfl(cf, (lane & 48) | (g * 4 + r));
            #pragma unroll
            for (int n = 0; n < 4; ++n)
                #pragma unroll
                for (int r = 0; r < 4; ++r) o[n][r] *= cfq[r];
            l_run *= cf;
            m_run = mn;
        }

        const float mb = m_run * LOG2E;
        float p[8];
        #pragma unroll
        for (int j = 0; j < 8; ++j)
            p[j] = (sv[j] <= -1e37f) ? 0.0f : exp2f(sv[j] * LOG2E - mb);
        float rs = ((p[0] + p[1]) + (p[2] + p[3])) + ((p[4] + p[5]) + (p[6] + p[7]));
        rs += __shfl_xor(rs, 16);
        rs += __shfl_xor(rs, 32);
        l_run += rs;

        // P -> wave-private LDS in A-frag layout: keys g*4+r -> kgrp g>>1
        bf16x4 p0, p1;
        #pragma unroll
        for (int r = 0; r < 4; ++r) { p0[r] = f2bf(p[r]); p1[r] = f2bf(p[4 + r]); }
        *(bf16x4*)&P_lds[w][g >> 1][c][(g & 1) * 4]       = p0;
        *(bf16x4*)&P_lds[w][2 + (g >> 1)][c][(g & 1) * 4] = p1;
        bf16x8 pa = *(bf16x8*)&P_lds[w][g][c][0];
        #pragma unroll
        for (int n = 0; n < 4; ++n)
            o[n] = __builtin_amdgcn_mfma_f32_16x16x32_bf16(pa, vb[n], o[n], 0, 0, 0);
    }

    __syncthreads();   // everyone done with P region before O overwrites it

    // publish per-wave partials (o rows: q = g*4+r; cols h = n*16+c)
    #pragma unroll
    for (int n = 0; n < 4; ++n)
        #pragma unroll
        for (int r = 0; r < 4; ++r)
            O_lds[w][g * 4 + r][n * 16 + c] = o[n][r];
    if (lane < 16) { M_lds[w][lane] = m_run; L_lds[w][lane] = l_run; }
    __syncthreads();

    // merge 8 segments: 512 threads cover 16x64 outputs, 2 cols each
    const int row  = tid >> 5;
    const int col0 = (tid & 31) * 2;
    float M = -INFINITY;
    #pragma unroll
    for (int i = 0; i < 8; ++i) M = fmaxf(M, M_lds[i][row]);
    float L = 0.0f, a0 = 0.0f, a1 = 0.0f;
    #pragma unroll
    for (int i = 0; i < 8; ++i) {
        float wgt = exp2f((M_lds[i][row] - M) * LOG2E);
        L  += L_lds[i][row] * wgt;
        a0 += O_lds[i][row][col0]     * wgt;
        a1 += O_lds[i][row][col0 + 1] * wgt;
    }
    float inv = 1.0f / L;
    float* Ob = out + (size_t)(b * SEQ + qbase + row) * HEAD;
    Ob[col0]     = a0 * inv;
    Ob[col0 + 1] = a1 * inv;
}

extern "C" void kernel_launch(void* const* d_in, const int* in_sizes, int n_in,
                              void* d_out, int out_size, void* d_ws, size_t ws_size,
                              hipStream_t stream)
{
    // setup_inputs order: key_input, query_input, value_input, mask, Wq, Wk, Wv
    const float* key_in   = (const float*)d_in[0];
    const float* query_in = (const float*)d_in[1];
    const float* value_in = (const float*)d_in[2];
    const void*  mask     = d_in[3];
    const float* Wq = (const float*)d_in[4];
    const float* Wk = (const float*)d_in[5];
    const float* Wv = (const float*)d_in[6];

    char* ws = (char*)d_ws;
    short* Qw  = (short*)ws;                            // 1 MB
    short* Kw  = Qw + (size_t)BATCH * SEQ * HEAD;       // 1 MB
    short* Vtw = Kw + (size_t)BATCH * SEQ * HEAD;       // 1 MB
    unsigned long long* packed =
        (unsigned long long*)(ws + (size_t)3 * BATCH * SEQ * HEAD * sizeof(short));  // 2 MB
    short* Wt  = (short*)((char*)packed + (size_t)NCHUNK * 8);   // 384 KB
    int* mflag = (int*)((char*)Wt + (size_t)3 * HEAD * DIM * sizeof(short));

    wconv_detect_kernel<<<dim3(16, 3), 256, 0, stream>>>(
        Wq, Wk, Wv, Wt, (const unsigned int*)mask, mflag);

    proj9_kernel<<<1536, 256, 0, stream>>>(
        query_in, key_in, value_in, Wt, Qw, Kw, Vtw);

    pack_kernel<<<512, 256, 0, stream>>>(mask, mflag, packed);

    attn_kernel<<<dim3(SEQ / 16, BATCH), 512, 0, stream>>>(
        Qw, Kw, Vtw, (const unsigned int*)packed, (float*)d_out);
}

// Round 14
// 81.118 us; speedup vs baseline: 1.0234x; 1.0234x over previous
//
#include <hip/hip_runtime.h>
#include <hip/hip_bf16.h>
#include <math.h>

#define BATCH 4
#define SEQ   2048
#define DIM   1024
#define HEAD  64
#define NCHUNK ((BATCH * SEQ * SEQ) / 64)   // 262144 64-bool chunks

typedef __attribute__((ext_vector_type(8))) short bf16x8;
typedef __attribute__((ext_vector_type(4))) short bf16x4;
typedef __attribute__((ext_vector_type(4))) float f32x4;

static __device__ __forceinline__ short f2bf(float f) {
    union { float f; unsigned u; } v;
    v.f = f;
    unsigned r = v.u + 0x7fffu + ((v.u >> 16) & 1u);   // RNE
    return (short)(r >> 16);
}

// ---------------------------------------------------------------------------
// Mask dtype self-detection (bool-as-byte vs int32). int32 bools are {0,1};
// packed bytes read as u32 exceed 1 w.p. 7/8 per word.
// ---------------------------------------------------------------------------
__global__ void detect_mask_kernel(const unsigned int* __restrict__ m,
                                   int* __restrict__ flag) {
    int lane = threadIdx.x & 63;
    bool weird = false;
    for (int i = lane; i < 1024; i += 64) weird |= (m[i] > 1u);
    unsigned long long b = __ballot(weird);
    if (threadIdx.x == 0) *flag = (b != 0ull) ? 1 : 0;
}

// ---------------------------------------------------------------------------
// Projection (R2 structure, warm-fast: ~14 us in L3-warm timed replays).
// X[8192,1024](f32) @ W[1024,64](f32) -> bf16. grid (128, 3): y selects
// (query@Wq->Q, key@Wk->K, value@Wv->Vt). 256 threads (4 waves), 64x64
// output tile, K-chunks of 32, frag-major LDS staging ([kgrp][row][8]) with
// cooperative 128B-dense loads; barrier per chunk. NOTE: cold-pass rocprof
// shows ~50 us — the bench times warm replays where this is ~3x faster than
// every register/gload variant tried in R5-R13.
// ---------------------------------------------------------------------------
__global__ __launch_bounds__(256) void proj_kernel(
    const float* __restrict__ Xq, const float* __restrict__ Xk, const float* __restrict__ Xv,
    const float* __restrict__ Wq, const float* __restrict__ Wk, const float* __restrict__ Wv,
    short* __restrict__ Q, short* __restrict__ K, short* __restrict__ Vt)
{
    const int which = blockIdx.y;
    const float* __restrict__ X = (which == 0) ? Xq : (which == 1) ? Xk : Xv;
    const float* __restrict__ W = (which == 0) ? Wq : (which == 1) ? Wk : Wv;

    const int row0 = blockIdx.x * 64;
    const int tid  = threadIdx.x;
    const int lane = tid & 63;
    const int wv   = tid >> 6;          // wave 0..3, owns rows wv*16..+15
    const int g    = lane >> 4;         // lane group 0..3
    const int c    = lane & 15;

    __shared__ __align__(16) short A_lds [4][64][8];   // [kgrp][row][8]
    __shared__ __align__(16) short Bt_lds[4][64][8];   // [dgrp][h][8]

    f32x4 acc[4];
    #pragma unroll
    for (int n = 0; n < 4; ++n) acc[n] = (f32x4)0.0f;

    const int arow = tid >> 2, ak8 = tid & 3;   // A staging assignment
    const int bh   = tid & 63, bd  = tid >> 6;  // W staging assignment

    for (int kc = 0; kc < DIM / 32; ++kc) {
        const int kbase = kc * 32;
        // stage A: 8 f32 per thread -> 8 bf16, one b128 LDS store
        {
            const float* src = X + (size_t)(row0 + arow) * DIM + kbase + ak8 * 8;
            f32x4 x0 = *(const f32x4*)(src);
            f32x4 x1 = *(const f32x4*)(src + 4);
            bf16x8 a;
            a[0]=f2bf(x0[0]); a[1]=f2bf(x0[1]); a[2]=f2bf(x0[2]); a[3]=f2bf(x0[3]);
            a[4]=f2bf(x1[0]); a[5]=f2bf(x1[1]); a[6]=f2bf(x1[2]); a[7]=f2bf(x1[3]);
            *(bf16x8*)&A_lds[ak8][arow][0] = a;
        }
        // stage W^T: 8 coalesced strided f32 loads per thread
        {
            bf16x8 bbv;
            #pragma unroll
            for (int j = 0; j < 8; ++j)
                bbv[j] = f2bf(W[(size_t)(kbase + bd * 8 + j) * HEAD + bh]);
            *(bf16x8*)&Bt_lds[bd][bh][0] = bbv;
        }
        __syncthreads();

        bf16x8 av = *(bf16x8*)&A_lds[g][wv * 16 + c][0];
        #pragma unroll
        for (int n = 0; n < 4; ++n) {
            bf16x8 bv = *(bf16x8*)&Bt_lds[g][n * 16 + c][0];
            acc[n] = __builtin_amdgcn_mfma_f32_16x16x32_bf16(av, bv, acc[n], 0, 0, 0);
        }
        __syncthreads();
    }

    // D layout: col = lane&15, row = (lane>>4)*4 + reg   [measured m89]
    if (which < 2) {
        short* dst = (which == 0) ? Q : K;
        #pragma unroll
        for (int n = 0; n < 4; ++n)
            #pragma unroll
            for (int r = 0; r < 4; ++r) {
                int row = row0 + wv * 16 + g * 4 + r;
                dst[(size_t)row * HEAD + n * 16 + c] = f2bf(acc[n][r]);
            }
    } else {
        #pragma unroll
        for (int n = 0; n < 4; ++n)
            #pragma unroll
            for (int r = 0; r < 4; ++r) {
                int row = row0 + wv * 16 + g * 4 + r;   // global b*S+s
                int b = row >> 11, s = row & (SEQ - 1);
                int h = n * 16 + c;
                Vt[((size_t)b * HEAD + h) * SEQ + s] = f2bf(acc[n][r]);
            }
    }
}

// ---------------------------------------------------------------------------
// Mask bit-pack: 16 independent 256B loads in flight per wave (6.1 TB/s),
// 512 blocks x 4 waves; wave owns 128 consecutive chunks.
// ---------------------------------------------------------------------------
__global__ __launch_bounds__(256) void pack_kernel(
    const void* __restrict__ mask, const int* __restrict__ mflag,
    unsigned long long* __restrict__ packed)
{
    const int lane = threadIdx.x & 63;
    const int gw   = blockIdx.x * 4 + (threadIdx.x >> 6);   // 0..2047
    const int c0   = gw * 128;
    const int useByte = *mflag;
    if (useByte) {
        const unsigned char* mb = (const unsigned char*)mask;
        for (int i = 0; i < 8; ++i) {
            unsigned char v[16];
            #pragma unroll
            for (int j = 0; j < 16; ++j)
                v[j] = mb[(size_t)(c0 + i * 16 + j) * 64 + lane];
            #pragma unroll
            for (int j = 0; j < 16; ++j) {
                unsigned long long bb = __ballot(v[j] != 0);
                if (lane == 0) packed[c0 + i * 16 + j] = bb;
            }
        }
    } else {
        const unsigned int* mw = (const unsigned int*)mask;
        for (int i = 0; i < 8; ++i) {
            unsigned int v[16];
            #pragma unroll
            for (int j = 0; j < 16; ++j)
                v[j] = mw[(size_t)(c0 + i * 16 + j) * 64 + lane];
            #pragma unroll
            for (int j = 0; j < 16; ++j) {
                unsigned long long bb = __ballot(v[j] != 0);
                if (lane == 0) packed[c0 + i * 16 + j] = bb;
            }
        }
    }
}

// ---------------------------------------------------------------------------
// Flash attention: grid (S/16, B), 512 threads = 8 waves; wave w owns keys
// [w*256,(w+1)*256). Swapped QK^T (S^T = mfma(K,Q)) puts a full q-row in-lane:
// softmax reduce = in-lane tree + 2 shfl_xor. Mask preloaded as 8 bit-words
// per lane. Defer-max rescale (THR=8). P->LDS transpose -> PV MFMA.
// ---------------------------------------------------------------------------
__global__ __launch_bounds__(512, 4) void attn_kernel(
    const short* __restrict__ Q, const short* __restrict__ K, const short* __restrict__ Vt,
    const unsigned int* __restrict__ packed, float* __restrict__ out)
{
    const int qbase = blockIdx.x * 16;
    const int b     = blockIdx.y;
    const int tid  = threadIdx.x;
    const int lane = tid & 63;
    const int w    = tid >> 6;          // wave 0..7 = key segment
    const int g    = lane >> 4;
    const int c    = lane & 15;

    const short* Qb = Q  + (size_t)(b * SEQ + qbase) * HEAD;
    const short* Kb = K  + (size_t)b * SEQ * HEAD;
    const short* Vb = Vt + (size_t)b * HEAD * SEQ;

    // LDS: P (loop phase, 8KB) aliases O (merge phase, 32KB); M/L after.
    __shared__ __align__(16) unsigned char smem[32768 + 1024];
    short (*P_lds)[4][16][8] = (short (*)[4][16][8])smem;   // [wave][kgrp][q][8]
    float (*O_lds)[16][64]   = (float (*)[16][64])smem;     // [wave][q][h]
    float (*M_lds)[16] = (float (*)[16])(smem + 32768);     // [wave][q]
    float (*L_lds)[16] = (float (*)[16])(smem + 32768 + 512);

    // per-lane mask bits for q = qbase+c, keys w*256..w*256+255 (8 u32 words)
    const unsigned int* pw = packed + (size_t)(b * SEQ + qbase + c) * 64 + w * 8;
    unsigned int mwords[8];
    #pragma unroll
    for (int i = 0; i < 8; ++i) mwords[i] = pw[i];

    // Q as B-operand fragments (col q = c, k = head dim)
    bf16x8 qb0 = *(const bf16x8*)&Qb[c * HEAD + g * 8];
    bf16x8 qb1 = *(const bf16x8*)&Qb[c * HEAD + 32 + g * 8];

    float m_run = -INFINITY, l_run = 0.0f;
    f32x4 o[4];
    #pragma unroll
    for (int n = 0; n < 4; ++n) o[n] = (f32x4)0.0f;

    const float scale = 0.125f;                    // HEAD^-0.5
    const float LOG2E = 1.44269504088896340736f;

    for (int i = 0; i < 8; ++i) {
        const int kt = w * 8 + i;                  // key tile of 32
        const short* Kt = Kb + (size_t)kt * 32 * HEAD;

        // V^T B-fragments (issued early, independent of QK chain)
        bf16x8 vb[4];
        #pragma unroll
        for (int n = 0; n < 4; ++n)
            vb[n] = *(const bf16x8*)&Vb[(size_t)(n * 16 + c) * SEQ + kt * 32 + g * 8];

        // K as A-operand (row = key = c / 16+c, k = head dim)
        bf16x8 ka00 = *(const bf16x8*)&Kt[c * HEAD + g * 8];
        bf16x8 ka01 = *(const bf16x8*)&Kt[c * HEAD + 32 + g * 8];
        bf16x8 ka10 = *(const bf16x8*)&Kt[(16 + c) * HEAD + g * 8];
        bf16x8 ka11 = *(const bf16x8*)&Kt[(16 + c) * HEAD + 32 + g * 8];

        // S^T tiles: lane holds q=c, keys g*4+r (s0) and 16+g*4+r (s1)
        f32x4 s0 = (f32x4)0.0f, s1 = (f32x4)0.0f;
        s0 = __builtin_amdgcn_mfma_f32_16x16x32_bf16(ka00, qb0, s0, 0, 0, 0);
        s0 = __builtin_amdgcn_mfma_f32_16x16x32_bf16(ka01, qb1, s0, 0, 0, 0);
        s1 = __builtin_amdgcn_mfma_f32_16x16x32_bf16(ka10, qb0, s1, 0, 0, 0);
        s1 = __builtin_amdgcn_mfma_f32_16x16x32_bf16(ka11, qb1, s1, 0, 0, 0);

        // scale + mask from preloaded bits (bit j of word = key kt*32+j)
        const unsigned int mw32 = mwords[i];
        float sv[8];
        #pragma unroll
        for (int r = 0; r < 4; ++r) {
            sv[r]     = ((mw32 >> (g * 4 + r)) & 1u)      ? -INFINITY : s0[r] * scale;
            sv[4 + r] = ((mw32 >> (16 + g * 4 + r)) & 1u) ? -INFINITY : s1[r] * scale;
        }

        // row max: in-lane tree + cross-group (lanes c, c+16, c+32, c+48)
        float mx = fmaxf(fmaxf(fmaxf(sv[0], sv[1]), fmaxf(sv[2], sv[3])),
                         fmaxf(fmaxf(sv[4], sv[5]), fmaxf(sv[6], sv[7])));
        mx = fmaxf(mx, __shfl_xor(mx, 16));
        mx = fmaxf(mx, __shfl_xor(mx, 32));

        // defer-max: rescale only when max grows past threshold (rare)
        if (!__all(mx <= m_run + 8.0f)) {
            float mn = fmaxf(m_run, mx);
            float cf = (m_run == mn) ? 1.0f : exp2f((m_run - mn) * LOG2E);
            float cfq[4];
            #pragma unroll
            for (int r = 0; r < 4; ++r)
                cfq[r] = __shfl(cf, (lane & 48) | (g * 4 + r));
            #pragma unroll
            for (int n = 0; n < 4; ++n)
                #pragma unroll
                for (int r = 0; r < 4; ++r) o[n][r] *= cfq[r];
            l_run *= cf;
            m_run = mn;
        }

        const float mb = m_run * LOG2E;
        float p[8];
        #pragma unroll
        for (int j = 0; j < 8; ++j)
            p[j] = (sv[j] <= -1e37f) ? 0.0f : exp2f(sv[j] * LOG2E - mb);
        float rs = ((p[0] + p[1]) + (p[2] + p[3])) + ((p[4] + p[5]) + (p[6] + p[7]));
        rs += __shfl_xor(rs, 16);
        rs += __shfl_xor(rs, 32);
        l_run += rs;

        // P -> wave-private LDS in A-frag layout: keys g*4+r -> kgrp g>>1
        bf16x4 p0, p1;
        #pragma unroll
        for (int r = 0; r < 4; ++r) { p0[r] = f2bf(p[r]); p1[r] = f2bf(p[4 + r]); }
        *(bf16x4*)&P_lds[w][g >> 1][c][(g & 1) * 4]       = p0;
        *(bf16x4*)&P_lds[w][2 + (g >> 1)][c][(g & 1) * 4] = p1;
        bf16x8 pa = *(bf16x8*)&P_lds[w][g][c][0];
        #pragma unroll
        for (int n = 0; n < 4; ++n)
            o[n] = __builtin_amdgcn_mfma_f32_16x16x32_bf16(pa, vb[n], o[n], 0, 0, 0);
    }

    __syncthreads();   // everyone done with P region before O overwrites it

    // publish per-wave partials (o rows: q = g*4+r; cols h = n*16+c)
    #pragma unroll
    for (int n = 0; n < 4; ++n)
        #pragma unroll
        for (int r = 0; r < 4; ++r)
            O_lds[w][g * 4 + r][n * 16 + c] = o[n][r];
    if (lane < 16) { M_lds[w][lane] = m_run; L_lds[w][lane] = l_run; }
    __syncthreads();

    // merge 8 segments: 512 threads cover 16x64 outputs, 2 cols each
    const int row  = tid >> 5;
    const int col0 = (tid & 31) * 2;
    float M = -INFINITY;
    #pragma unroll
    for (int i = 0; i < 8; ++i) M = fmaxf(M, M_lds[i][row]);
    float L = 0.0f, a0 = 0.0f, a1 = 0.0f;
    #pragma unroll
    for (int i = 0; i < 8; ++i) {
        float wgt = exp2f((M_lds[i][row] - M) * LOG2E);
        L  += L_lds[i][row] * wgt;
        a0 += O_lds[i][row][col0]     * wgt;
        a1 += O_lds[i][row][col0 + 1] * wgt;
    }
    float inv = 1.0f / L;
    float* Ob = out + (size_t)(b * SEQ + qbase + row) * HEAD;
    Ob[col0]     = a0 * inv;
    Ob[col0 + 1] = a1 * inv;
}

extern "C" void kernel_launch(void* const* d_in, const int* in_sizes, int n_in,
                              void* d_out, int out_size, void* d_ws, size_t ws_size,
                              hipStream_t stream)
{
    // setup_inputs order: key_input, query_input, value_input, mask, Wq, Wk, Wv
    const float* key_in   = (const float*)d_in[0];
    const float* query_in = (const float*)d_in[1];
    const float* value_in = (const float*)d_in[2];
    const void*  mask     = d_in[3];
    const float* Wq = (const float*)d_in[4];
    const float* Wk = (const float*)d_in[5];
    const float* Wv = (const float*)d_in[6];

    char* ws = (char*)d_ws;
    short* Qw  = (short*)ws;                            // 1 MB
    short* Kw  = Qw + (size_t)BATCH * SEQ * HEAD;       // 1 MB
    short* Vtw = Kw + (size_t)BATCH * SEQ * HEAD;       // 1 MB
    unsigned long long* packed =
        (unsigned long long*)(ws + (size_t)3 * BATCH * SEQ * HEAD * sizeof(short));  // 2 MB
    int* mflag = (int*)((char*)packed + (size_t)NCHUNK * 8);

    detect_mask_kernel<<<1, 64, 0, stream>>>((const unsigned int*)mask, mflag);

    proj_kernel<<<dim3(BATCH * SEQ / 64, 3), 256, 0, stream>>>(
        query_in, key_in, value_in, Wq, Wk, Wv, Qw, Kw, Vtw);

    pack_kernel<<<512, 256, 0, stream>>>(mask, mflag, packed);

    attn_kernel<<<dim3(SEQ / 16, BATCH), 512, 0, stream>>>(
        Qw, Kw, Vtw, (const unsigned int*)packed, (float*)d_out);
}

// Round 15
// 76.658 us; speedup vs baseline: 1.0830x; 1.0582x over previous
//
#include <hip/hip_runtime.h>
#include <hip/hip_bf16.h>
#include <math.h>

#define BATCH 4
#define SEQ   2048
#define DIM   1024
#define HEAD  64
#define NCHUNK ((BATCH * SEQ * SEQ) / 64)   // 262144 64-bool chunks

typedef __attribute__((ext_vector_type(8))) short bf16x8;
typedef __attribute__((ext_vector_type(4))) short bf16x4;
typedef __attribute__((ext_vector_type(4))) float f32x4;

static __device__ __forceinline__ short f2bf(float f) {
    __hip_bfloat16 h = __float2bfloat16(f);     // RNE
    return *reinterpret_cast<short*>(&h);
}

// ---------------------------------------------------------------------------
// Prelude: W[1024][64] f32 -> frag-major Wt2[which][k/32][64][32] bf16, so a
// proj wave's B-frag load (n,c,g lanes) is one contiguous 1KB segment.
// Plus mask dtype detect (int32 bools are {0,1}; byte-bools read as u32
// exceed 1 w.p. 7/8 per word).
// ---------------------------------------------------------------------------
__global__ __launch_bounds__(256) void wconv_detect_kernel(
    const float* __restrict__ Wq, const float* __restrict__ Wk, const float* __restrict__ Wv,
    short* __restrict__ Wt, const unsigned int* __restrict__ mask_u32,
    int* __restrict__ mflag)
{
    const int which = blockIdx.y;
    const float* __restrict__ W = (which == 0) ? Wq : (which == 1) ? Wk : Wv;
    short* __restrict__ Wtw = Wt + (size_t)which * HEAD * DIM;

    const int h  = threadIdx.x & 63;
    const int k0 = blockIdx.x * 64 + (threadIdx.x >> 6) * 16;
    #pragma unroll
    for (int j = 0; j < 16; ++j) {
        int k = k0 + j;
        Wtw[((size_t)(k >> 5) * 64 + h) * 32 + (k & 31)] =
            f2bf(W[(size_t)k * HEAD + h]);
    }

    if (blockIdx.x == 0 && blockIdx.y == 0 && threadIdx.x < 64) {
        int lane = threadIdx.x;
        bool weird = false;
        for (int i = lane; i < 1024; i += 64) weird |= (mask_u32[i] > 1u);
        unsigned long long b = __ballot(weird);
        if (lane == 0) *mflag = (b != 0ull) ? 1 : 0;
    }
}

// ---------------------------------------------------------------------------
// Fused prep (R12-best, 73.9 us config): grid 2048 x 256.
//   blocks [0,512):    mask bit-pack (67 MB stream)
//   blocks [512,2048): projection (proj5 core, best measured proj: 41.5 us)
// ---------------------------------------------------------------------------
__global__ __launch_bounds__(256, 4) void prep_kernel(
    const float* __restrict__ Xq, const float* __restrict__ Xk, const float* __restrict__ Xv,
    const short* __restrict__ Wt, const void* __restrict__ mask,
    const int* __restrict__ mflag, unsigned long long* __restrict__ packed,
    short* __restrict__ Q, short* __restrict__ K, short* __restrict__ Vt)
{
    const int bx  = blockIdx.x;
    const int tid = threadIdx.x;
    const int lane = tid & 63;
    const int w    = tid >> 6;

    if (bx < 512) {
        // ------------------------- mask pack -------------------------
        const int gw = bx * 4 + w;                // 0..2047
        const int c0 = gw * 128;
        const int useByte = *mflag;
        if (useByte) {
            const unsigned char* mb = (const unsigned char*)mask;
            for (int i = 0; i < 8; ++i) {
                unsigned char v[16];
                #pragma unroll
                for (int j = 0; j < 16; ++j)
                    v[j] = mb[(size_t)(c0 + i * 16 + j) * 64 + lane];
                #pragma unroll
                for (int j = 0; j < 16; ++j) {
                    unsigned long long bb = __ballot(v[j] != 0);
                    if (lane == 0) packed[c0 + i * 16 + j] = bb;
                }
            }
        } else {
            const unsigned int* mw = (const unsigned int*)mask;
            for (int i = 0; i < 8; ++i) {
                unsigned int v[16];
                #pragma unroll
                for (int j = 0; j < 16; ++j)
                    v[j] = mw[(size_t)(c0 + i * 16 + j) * 64 + lane];
                #pragma unroll
                for (int j = 0; j < 16; ++j) {
                    unsigned long long bb = __ballot(v[j] != 0);
                    if (lane == 0) packed[c0 + i * 16 + j] = bb;
                }
            }
        }
        return;
    }

    // ------------------------- projection (proj5 core) -------------------------
    __shared__ float O_lds[4][16][64];          // [wave][row][col] partials

    const int pi    = bx - 512;
    const int which = pi >> 9;                  // 0:Q 1:K 2:V
    const int row0  = (pi & 511) * 16;          // global row (b*S+s)
    const float* __restrict__ X = (which == 0) ? Xq : (which == 1) ? Xk : Xv;
    const short* __restrict__ Wtw = Wt + (size_t)which * HEAD * DIM;

    const int g = lane >> 4;
    const int c = lane & 15;

    const float* __restrict__ Xp = X + (size_t)(row0 + c) * DIM + w * 256 + g * 8;
    const short* __restrict__ Wp = Wtw + (size_t)(w * 8) * 2048 + c * 32 + g * 8;

    f32x4 acc[4];
    #pragma unroll
    for (int n = 0; n < 4; ++n) acc[n] = (f32x4)0.0f;

    #pragma unroll
    for (int half = 0; half < 2; ++half) {
        f32x4 xa[4], xb[4];
        #pragma unroll
        for (int s = 0; s < 4; ++s) {
            xa[s] = *(const f32x4*)(Xp + half * 128 + s * 32);
            xb[s] = *(const f32x4*)(Xp + half * 128 + s * 32 + 4);
        }
        bf16x8 wf[16];
        #pragma unroll
        for (int s = 0; s < 4; ++s)
            #pragma unroll
            for (int n = 0; n < 4; ++n)
                wf[s * 4 + n] = *(const bf16x8*)(Wp + (size_t)(half * 4 + s) * 2048
                                                 + n * 512);
        #pragma unroll
        for (int s = 0; s < 4; ++s) {
            bf16x8 a;
            a[0]=f2bf(xa[s][0]); a[1]=f2bf(xa[s][1]); a[2]=f2bf(xa[s][2]); a[3]=f2bf(xa[s][3]);
            a[4]=f2bf(xb[s][0]); a[5]=f2bf(xb[s][1]); a[6]=f2bf(xb[s][2]); a[7]=f2bf(xb[s][3]);
            #pragma unroll
            for (int n = 0; n < 4; ++n)
                acc[n] = __builtin_amdgcn_mfma_f32_16x16x32_bf16(a, wf[s * 4 + n],
                                                                 acc[n], 0, 0, 0);
        }
    }

    #pragma unroll
    for (int n = 0; n < 4; ++n)
        #pragma unroll
        for (int r = 0; r < 4; ++r)
            O_lds[w][g * 4 + r][n * 16 + c] = acc[n][r];
    __syncthreads();

    if (which < 2) {
        short* dst = (which == 0) ? Q : K;
        const int trow = tid >> 4, c4 = (tid & 15) * 4;
        f32x4 sum = *(const f32x4*)&O_lds[0][trow][c4];
        #pragma unroll
        for (int i = 1; i < 4; ++i) {
            f32x4 t = *(const f32x4*)&O_lds[i][trow][c4];
            sum[0] += t[0]; sum[1] += t[1]; sum[2] += t[2]; sum[3] += t[3];
        }
        bf16x4 pk;
        #pragma unroll
        for (int j = 0; j < 4; ++j) pk[j] = f2bf(sum[j]);
        *(bf16x4*)&dst[(size_t)(row0 + trow) * HEAD + c4] = pk;
    } else {
        const int h = tid & 63, r4 = (tid >> 6) * 4;
        const int b = row0 >> 11, sb = row0 & (SEQ - 1);
        bf16x4 pk;
        #pragma unroll
        for (int j = 0; j < 4; ++j) {
            float v = O_lds[0][r4 + j][h] + O_lds[1][r4 + j][h]
                    + O_lds[2][r4 + j][h] + O_lds[3][r4 + j][h];
            pk[j] = f2bf(v);
        }
        *(bf16x4*)&Vt[((size_t)(b * HEAD + h)) * SEQ + sb + r4] = pk;
    }
}

// ---------------------------------------------------------------------------
// Flash attention v4: grid (S/16, B), 512 threads = 8 waves; wave w owns keys
// [w*256,(w+1)*256) in 4 iterations of KVBLK=64 (was 8 x 32). Swapped QK^T
// puts a full q-row in-lane; per 64 keys: one 16-element in-lane tree +
// 2 shfl_xor (was 2x8-tree + 4 shfl), one defer-max check, one P-LDS
// roundtrip. 16 loads issued per iteration before first use (MLP).
// ---------------------------------------------------------------------------
__global__ __launch_bounds__(512, 4) void attn_kernel(
    const short* __restrict__ Q, const short* __restrict__ K, const short* __restrict__ Vt,
    const unsigned int* __restrict__ packed, float* __restrict__ out)
{
    const int qbase = blockIdx.x * 16;
    const int b     = blockIdx.y;
    const int tid  = threadIdx.x;
    const int lane = tid & 63;
    const int w    = tid >> 6;          // wave 0..7 = key segment
    const int g    = lane >> 4;
    const int c    = lane & 15;

    const short* Qb = Q  + (size_t)(b * SEQ + qbase) * HEAD;
    const short* Kb = K  + (size_t)b * SEQ * HEAD;
    const short* Vb = Vt + (size_t)b * HEAD * SEQ;

    // LDS: P (loop phase, 16KB) aliases O (merge phase, 32KB); M/L after.
    __shared__ __align__(16) unsigned char smem[32768 + 1024];
    short (*P_lds)[8][16][8] = (short (*)[8][16][8])smem;   // [wave][key/8][q][8]
    float (*O_lds)[16][64]   = (float (*)[16][64])smem;     // [wave][q][h]
    float (*M_lds)[16] = (float (*)[16])(smem + 32768);     // [wave][q]
    float (*L_lds)[16] = (float (*)[16])(smem + 32768 + 512);

    // per-lane mask bits for q = qbase+c, keys w*256..w*256+255 (8 u32 words)
    const unsigned int* pw = packed + (size_t)(b * SEQ + qbase + c) * 64 + w * 8;
    unsigned int mwords[8];
    #pragma unroll
    for (int i = 0; i < 8; ++i) mwords[i] = pw[i];

    // Q as B-operand fragments (col q = c, k = head dim)
    bf16x8 qb0 = *(const bf16x8*)&Qb[c * HEAD + g * 8];
    bf16x8 qb1 = *(const bf16x8*)&Qb[c * HEAD + 32 + g * 8];

    float m_run = -INFINITY, l_run = 0.0f;
    f32x4 o[4];
    #pragma unroll
    for (int n = 0; n < 4; ++n) o[n] = (f32x4)0.0f;

    const float scale = 0.125f;                    // HEAD^-0.5
    const float LOG2E = 1.44269504088896340736f;

    for (int j = 0; j < 4; ++j) {
        const int key0 = w * 256 + j * 64;         // 64-key tile base
        const short* Kt = Kb + (size_t)key0 * HEAD;

        // V^T B-fragments for both 32-key halves (8 x 16B, issued early)
        bf16x8 vb0[4], vb1[4];
        #pragma unroll
        for (int n = 0; n < 4; ++n) {
            const short* vrow = &Vb[(size_t)(n * 16 + c) * SEQ + key0 + g * 8];
            vb0[n] = *(const bf16x8*)(vrow);
            vb1[n] = *(const bf16x8*)(vrow + 32);
        }

        // QK^T over 64 keys: 4 key-groups x 2 chained MFMAs
        f32x4 s[4];
        #pragma unroll
        for (int kg = 0; kg < 4; ++kg) {
            bf16x8 ka0 = *(const bf16x8*)&Kt[(kg * 16 + c) * HEAD + g * 8];
            bf16x8 ka1 = *(const bf16x8*)&Kt[(kg * 16 + c) * HEAD + 32 + g * 8];
            f32x4 sv = (f32x4)0.0f;
            sv = __builtin_amdgcn_mfma_f32_16x16x32_bf16(ka0, qb0, sv, 0, 0, 0);
            sv = __builtin_amdgcn_mfma_f32_16x16x32_bf16(ka1, qb1, sv, 0, 0, 0);
            s[kg] = sv;
        }

        // scale + mask from preloaded bits. key = key0 + kg*16 + g*4 + r:
        // word = mwords[2j + (kg>>1)], bit = (kg&1)*16 + g*4 + r
        float sv[16];
        #pragma unroll
        for (int kg = 0; kg < 4; ++kg) {
            const unsigned int mw32 = mwords[2 * j + (kg >> 1)];
            #pragma unroll
            for (int r = 0; r < 4; ++r)
                sv[kg * 4 + r] = ((mw32 >> ((kg & 1) * 16 + g * 4 + r)) & 1u)
                                 ? -INFINITY : s[kg][r] * scale;
        }

        // row max: 16-element in-lane tree + 2 cross-group shfl
        float mx = sv[0];
        #pragma unroll
        for (int t = 1; t < 16; ++t) mx = fmaxf(mx, sv[t]);
        mx = fmaxf(mx, __shfl_xor(mx, 16));
        mx = fmaxf(mx, __shfl_xor(mx, 32));

        // defer-max: rescale only when max grows past threshold (rare)
        if (!__all(mx <= m_run + 8.0f)) {
            float mn = fmaxf(m_run, mx);
            float cf = (m_run == mn) ? 1.0f : exp2f((m_run - mn) * LOG2E);
            float cfq[4];
            #pragma unroll
            for (int r = 0; r < 4; ++r)
                cfq[r] = __shfl(cf, (lane & 48) | (g * 4 + r));
            #pragma unroll
            for (int n = 0; n < 4; ++n)
                #pragma unroll
                for (int r = 0; r < 4; ++r) o[n][r] *= cfq[r];
            l_run *= cf;
            m_run = mn;
        }

        const float mb = m_run * LOG2E;
        float p[16];
        #pragma unroll
        for (int t = 0; t < 16; ++t)
            p[t] = (sv[t] <= -1e37f) ? 0.0f : exp2f(sv[t] * LOG2E - mb);
        float rs = 0.0f;
        #pragma unroll
        for (int t = 0; t < 16; ++t) rs += p[t];
        rs += __shfl_xor(rs, 16);
        rs += __shfl_xor(rs, 32);
        l_run += rs;

        // P -> wave-private LDS in A-frag layout:
        // key/8 index = kg*2 + (g>>1), elem = (g&1)*4 + r
        #pragma unroll
        for (int kg = 0; kg < 4; ++kg) {
            bf16x4 pk;
            #pragma unroll
            for (int r = 0; r < 4; ++r) pk[r] = f2bf(p[kg * 4 + r]);
            *(bf16x4*)&P_lds[w][kg * 2 + (g >> 1)][c][(g & 1) * 4] = pk;
        }
        // PV: two 32-key halves; pa covers keys h*32 + g*8 .. +8
        bf16x8 pa0 = *(bf16x8*)&P_lds[w][g][c][0];
        bf16x8 pa1 = *(bf16x8*)&P_lds[w][4 + g][c][0];
        #pragma unroll
        for (int n = 0; n < 4; ++n) {
            o[n] = __builtin_amdgcn_mfma_f32_16x16x32_bf16(pa0, vb0[n], o[n], 0, 0, 0);
            o[n] = __builtin_amdgcn_mfma_f32_16x16x32_bf16(pa1, vb1[n], o[n], 0, 0, 0);
        }
    }

    __syncthreads();   // everyone done with P region before O overwrites it

    // publish per-wave partials (o rows: q = g*4+r; cols h = n*16+c)
    #pragma unroll
    for (int n = 0; n < 4; ++n)
        #pragma unroll
        for (int r = 0; r < 4; ++r)
            O_lds[w][g * 4 + r][n * 16 + c] = o[n][r];
    if (lane < 16) { M_lds[w][lane] = m_run; L_lds[w][lane] = l_run; }
    __syncthreads();

    // merge 8 segments: 512 threads cover 16x64 outputs, 2 cols each
    const int row  = tid >> 5;
    const int col0 = (tid & 31) * 2;
    float M = -INFINITY;
    #pragma unroll
    for (int i = 0; i < 8; ++i) M = fmaxf(M, M_lds[i][row]);
    float L = 0.0f, a0 = 0.0f, a1 = 0.0f;
    #pragma unroll
    for (int i = 0; i < 8; ++i) {
        float wgt = exp2f((M_lds[i][row] - M) * LOG2E);
        L  += L_lds[i][row] * wgt;
        a0 += O_lds[i][row][col0]     * wgt;
        a1 += O_lds[i][row][col0 + 1] * wgt;
    }
    float inv = 1.0f / L;
    float* Ob = out + (size_t)(b * SEQ + qbase + row) * HEAD;
    Ob[col0]     = a0 * inv;
    Ob[col0 + 1] = a1 * inv;
}

extern "C" void kernel_launch(void* const* d_in, const int* in_sizes, int n_in,
                              void* d_out, int out_size, void* d_ws, size_t ws_size,
                              hipStream_t stream)
{
    // setup_inputs order: key_input, query_input, value_input, mask, Wq, Wk, Wv
    const float* key_in   = (const float*)d_in[0];
    const float* query_in = (const float*)d_in[1];
    const float* value_in = (const float*)d_in[2];
    const void*  mask     = d_in[3];
    const float* Wq = (const float*)d_in[4];
    const float* Wk = (const float*)d_in[5];
    const float* Wv = (const float*)d_in[6];

    char* ws = (char*)d_ws;
    short* Qw  = (short*)ws;                            // 1 MB
    short* Kw  = Qw + (size_t)BATCH * SEQ * HEAD;       // 1 MB
    short* Vtw = Kw + (size_t)BATCH * SEQ * HEAD;       // 1 MB
    unsigned long long* packed =
        (unsigned long long*)(ws + (size_t)3 * BATCH * SEQ * HEAD * sizeof(short));  // 2 MB
    short* Wt  = (short*)((char*)packed + (size_t)NCHUNK * 8);   // 384 KB
    int* mflag = (int*)((char*)Wt + (size_t)3 * HEAD * DIM * sizeof(short));

    wconv_detect_kernel<<<dim3(16, 3), 256, 0, stream>>>(
        Wq, Wk, Wv, Wt, (const unsigned int*)mask, mflag);

    prep_kernel<<<2048, 256, 0, stream>>>(
        query_in, key_in, value_in, Wt, mask, mflag, packed, Qw, Kw, Vtw);

    attn_kernel<<<dim3(SEQ / 16, BATCH), 512, 0, stream>>>(
        Qw, Kw, Vtw, (const unsigned int*)packed, (float*)d_out);
}

// Round 16
// 62.032 us; speedup vs baseline: 1.3383x; 1.2358x over previous
//
#include <hip/hip_runtime.h>
#include <hip/hip_bf16.h>
#include <math.h>

#define BATCH 4
#define SEQ   2048
#define DIM   1024
#define HEAD  64
#define NCHUNK ((BATCH * SEQ * SEQ) / 64)   // 262144 64-bool chunks

typedef __attribute__((ext_vector_type(8))) short bf16x8;
typedef __attribute__((ext_vector_type(4))) short bf16x4;
typedef __attribute__((ext_vector_type(4))) float f32x4;

static __device__ __forceinline__ short f2bf(float f) {
    __hip_bfloat16 h = __float2bfloat16(f);     // RNE
    return *reinterpret_cast<short*>(&h);
}

// ---------------------------------------------------------------------------
// Prelude: W[1024][64] f32 -> frag-major Wt2[which][k/32][64][32] bf16, so a
// proj wave's B-frag load (n,c,g lanes) is one contiguous 1KB segment.
// Plus mask dtype detect (int32 bools are {0,1}; byte-bools read as u32
// exceed 1 w.p. 7/8 per word).
// ---------------------------------------------------------------------------
__global__ __launch_bounds__(256) void wconv_detect_kernel(
    const float* __restrict__ Wq, const float* __restrict__ Wk, const float* __restrict__ Wv,
    short* __restrict__ Wt, const unsigned int* __restrict__ mask_u32,
    int* __restrict__ mflag)
{
    const int which = blockIdx.y;
    const float* __restrict__ W = (which == 0) ? Wq : (which == 1) ? Wk : Wv;
    short* __restrict__ Wtw = Wt + (size_t)which * HEAD * DIM;

    const int h  = threadIdx.x & 63;
    const int k0 = blockIdx.x * 64 + (threadIdx.x >> 6) * 16;
    #pragma unroll
    for (int j = 0; j < 16; ++j) {
        int k = k0 + j;
        Wtw[((size_t)(k >> 5) * 64 + h) * 32 + (k & 31)] =
            f2bf(W[(size_t)k * HEAD + h]);
    }

    if (blockIdx.x == 0 && blockIdx.y == 0 && threadIdx.x < 64) {
        int lane = threadIdx.x;
        bool weird = false;
        for (int i = lane; i < 1024; i += 64) weird |= (mask_u32[i] > 1u);
        unsigned long long b = __ballot(weird);
        if (lane == 0) *mflag = (b != 0ull) ? 1 : 0;
    }
}

// ---------------------------------------------------------------------------
// Fused prep (R12-best config): grid 2048 x 256.
//   blocks [0,512):    mask bit-pack (67 MB stream)
//   blocks [512,2048): projection (proj5 core, best measured proj: 41.5 us)
// ---------------------------------------------------------------------------
__global__ __launch_bounds__(256, 4) void prep_kernel(
    const float* __restrict__ Xq, const float* __restrict__ Xk, const float* __restrict__ Xv,
    const short* __restrict__ Wt, const void* __restrict__ mask,
    const int* __restrict__ mflag, unsigned long long* __restrict__ packed,
    short* __restrict__ Q, short* __restrict__ K, short* __restrict__ Vt)
{
    const int bx  = blockIdx.x;
    const int tid = threadIdx.x;
    const int lane = tid & 63;
    const int w    = tid >> 6;

    if (bx < 512) {
        // ------------------------- mask pack -------------------------
        const int gw = bx * 4 + w;                // 0..2047
        const int c0 = gw * 128;
        const int useByte = *mflag;
        if (useByte) {
            const unsigned char* mb = (const unsigned char*)mask;
            for (int i = 0; i < 8; ++i) {
                unsigned char v[16];
                #pragma unroll
                for (int j = 0; j < 16; ++j)
                    v[j] = mb[(size_t)(c0 + i * 16 + j) * 64 + lane];
                #pragma unroll
                for (int j = 0; j < 16; ++j) {
                    unsigned long long bb = __ballot(v[j] != 0);
                    if (lane == 0) packed[c0 + i * 16 + j] = bb;
                }
            }
        } else {
            const unsigned int* mw = (const unsigned int*)mask;
            for (int i = 0; i < 8; ++i) {
                unsigned int v[16];
                #pragma unroll
                for (int j = 0; j < 16; ++j)
                    v[j] = mw[(size_t)(c0 + i * 16 + j) * 64 + lane];
                #pragma unroll
                for (int j = 0; j < 16; ++j) {
                    unsigned long long bb = __ballot(v[j] != 0);
                    if (lane == 0) packed[c0 + i * 16 + j] = bb;
                }
            }
        }
        return;
    }

    // ------------------------- projection (proj5 core) -------------------------
    __shared__ float O_lds[4][16][64];          // [wave][row][col] partials

    const int pi    = bx - 512;
    const int which = pi >> 9;                  // 0:Q 1:K 2:V
    const int row0  = (pi & 511) * 16;          // global row (b*S+s)
    const float* __restrict__ X = (which == 0) ? Xq : (which == 1) ? Xk : Xv;
    const short* __restrict__ Wtw = Wt + (size_t)which * HEAD * DIM;

    const int g = lane >> 4;
    const int c = lane & 15;

    const float* __restrict__ Xp = X + (size_t)(row0 + c) * DIM + w * 256 + g * 8;
    const short* __restrict__ Wp = Wtw + (size_t)(w * 8) * 2048 + c * 32 + g * 8;

    f32x4 acc[4];
    #pragma unroll
    for (int n = 0; n < 4; ++n) acc[n] = (f32x4)0.0f;

    #pragma unroll
    for (int half = 0; half < 2; ++half) {
        f32x4 xa[4], xb[4];
        #pragma unroll
        for (int s = 0; s < 4; ++s) {
            xa[s] = *(const f32x4*)(Xp + half * 128 + s * 32);
            xb[s] = *(const f32x4*)(Xp + half * 128 + s * 32 + 4);
        }
        bf16x8 wf[16];
        #pragma unroll
        for (int s = 0; s < 4; ++s)
            #pragma unroll
            for (int n = 0; n < 4; ++n)
                wf[s * 4 + n] = *(const bf16x8*)(Wp + (size_t)(half * 4 + s) * 2048
                                                 + n * 512);
        #pragma unroll
        for (int s = 0; s < 4; ++s) {
            bf16x8 a;
            a[0]=f2bf(xa[s][0]); a[1]=f2bf(xa[s][1]); a[2]=f2bf(xa[s][2]); a[3]=f2bf(xa[s][3]);
            a[4]=f2bf(xb[s][0]); a[5]=f2bf(xb[s][1]); a[6]=f2bf(xb[s][2]); a[7]=f2bf(xb[s][3]);
            #pragma unroll
            for (int n = 0; n < 4; ++n)
                acc[n] = __builtin_amdgcn_mfma_f32_16x16x32_bf16(a, wf[s * 4 + n],
                                                                 acc[n], 0, 0, 0);
        }
    }

    #pragma unroll
    for (int n = 0; n < 4; ++n)
        #pragma unroll
        for (int r = 0; r < 4; ++r)
            O_lds[w][g * 4 + r][n * 16 + c] = acc[n][r];
    __syncthreads();

    if (which < 2) {
        short* dst = (which == 0) ? Q : K;
        const int trow = tid >> 4, c4 = (tid & 15) * 4;
        f32x4 sum = *(const f32x4*)&O_lds[0][trow][c4];
        #pragma unroll
        for (int i = 1; i < 4; ++i) {
            f32x4 t = *(const f32x4*)&O_lds[i][trow][c4];
            sum[0] += t[0]; sum[1] += t[1]; sum[2] += t[2]; sum[3] += t[3];
        }
        bf16x4 pk;
        #pragma unroll
        for (int j = 0; j < 4; ++j) pk[j] = f2bf(sum[j]);
        *(bf16x4*)&dst[(size_t)(row0 + trow) * HEAD + c4] = pk;
    } else {
        const int h = tid & 63, r4 = (tid >> 6) * 4;
        const int b = row0 >> 11, sb = row0 & (SEQ - 1);
        bf16x4 pk;
        #pragma unroll
        for (int j = 0; j < 4; ++j) {
            float v = O_lds[0][r4 + j][h] + O_lds[1][r4 + j][h]
                    + O_lds[2][r4 + j][h] + O_lds[3][r4 + j][h];
            pk[j] = f2bf(v);
        }
        *(bf16x4*)&Vt[((size_t)(b * HEAD + h)) * SEQ + sb + r4] = pk;
    }
}

// ---------------------------------------------------------------------------
// Flash attention v5: 256 blocks x 512 threads (8 waves). Block = (batch,
// 32 q-rows): bi&3 = batch -> batch lands only on XCDs {b, b+4}, so K/V/Q/
// packed (~1.3 MB/batch) are L2-RESIDENT per XCD (kills the cross-XCD L3
// traffic that bounded v3 at ~21 us). Wave w owns keys [w*256,(w+1)*256);
// each K/V fragment load now feeds TWO q-tiles (halves traffic + load count
// per q-row). Inner loop per 32-key tile = v3 (best measured): swapped QK^T,
// in-lane softmax, bit-mask words, defer-max, P->LDS->PV.
// ---------------------------------------------------------------------------
__global__ __launch_bounds__(512, 2) void attn_kernel(
    const short* __restrict__ Q, const short* __restrict__ K, const short* __restrict__ Vt,
    const unsigned int* __restrict__ packed, float* __restrict__ out)
{
    const int bi    = blockIdx.x;
    const int b     = bi & 3;            // XCD-friendly: batch -> XCDs {b, b+4}
    const int qbase = (bi >> 2) * 32;
    const int tid  = threadIdx.x;
    const int lane = tid & 63;
    const int w    = tid >> 6;          // wave 0..7 = key segment
    const int g    = lane >> 4;
    const int c    = lane & 15;

    const short* Qb = Q  + (size_t)(b * SEQ + qbase) * HEAD;
    const short* Kb = K  + (size_t)b * SEQ * HEAD;
    const short* Vb = Vt + (size_t)b * HEAD * SEQ;

    // LDS: P (loop phase, 16KB: 2 tiles) aliases O (merge phase, 32KB).
    __shared__ __align__(16) unsigned char smem[32768 + 1024];
    short (*P_lds)[2][4][16][8] = (short (*)[2][4][16][8])smem; // [wave][tile][kgrp][q][8]
    float (*O_lds)[16][64]      = (float (*)[16][64])smem;      // [wave][q][h]
    float (*M_lds)[16] = (float (*)[16])(smem + 32768);         // [wave][q]
    float (*L_lds)[16] = (float (*)[16])(smem + 32768 + 512);

    // per-lane mask bits: tile0 q = qbase+c, tile1 q = qbase+16+c
    const unsigned int* pw0 = packed + (size_t)(b * SEQ + qbase + c) * 64 + w * 8;
    unsigned int mw0[8], mw1[8];
    #pragma unroll
    for (int i = 0; i < 8; ++i) { mw0[i] = pw0[i]; mw1[i] = pw0[16 * 64 + i]; }

    // Q as B-operand fragments for both tiles
    bf16x8 qb0 = *(const bf16x8*)&Qb[c * HEAD + g * 8];
    bf16x8 qb1 = *(const bf16x8*)&Qb[c * HEAD + 32 + g * 8];
    bf16x8 qc0 = *(const bf16x8*)&Qb[(16 + c) * HEAD + g * 8];
    bf16x8 qc1 = *(const bf16x8*)&Qb[(16 + c) * HEAD + 32 + g * 8];

    float m0 = -INFINITY, l0 = 0.0f, m1 = -INFINITY, l1 = 0.0f;
    f32x4 o0[4], o1[4];
    #pragma unroll
    for (int n = 0; n < 4; ++n) { o0[n] = (f32x4)0.0f; o1[n] = (f32x4)0.0f; }

    const float scale = 0.125f;                    // HEAD^-0.5
    const float LOG2E = 1.44269504088896340736f;

    for (int i = 0; i < 8; ++i) {
        const int kt = w * 8 + i;                  // key tile of 32
        const short* Kt = Kb + (size_t)kt * 32 * HEAD;

        // V^T B-fragments (shared by both q-tiles)
        bf16x8 vb[4];
        #pragma unroll
        for (int n = 0; n < 4; ++n)
            vb[n] = *(const bf16x8*)&Vb[(size_t)(n * 16 + c) * SEQ + kt * 32 + g * 8];

        // K as A-operand (shared by both q-tiles)
        bf16x8 ka00 = *(const bf16x8*)&Kt[c * HEAD + g * 8];
        bf16x8 ka01 = *(const bf16x8*)&Kt[c * HEAD + 32 + g * 8];
        bf16x8 ka10 = *(const bf16x8*)&Kt[(16 + c) * HEAD + g * 8];
        bf16x8 ka11 = *(const bf16x8*)&Kt[(16 + c) * HEAD + 32 + g * 8];

        // ---- both tiles' QK^T (K frags reused) ----
        f32x4 s0t0 = (f32x4)0.0f, s1t0 = (f32x4)0.0f;
        s0t0 = __builtin_amdgcn_mfma_f32_16x16x32_bf16(ka00, qb0, s0t0, 0, 0, 0);
        s0t0 = __builtin_amdgcn_mfma_f32_16x16x32_bf16(ka01, qb1, s0t0, 0, 0, 0);
        s1t0 = __builtin_amdgcn_mfma_f32_16x16x32_bf16(ka10, qb0, s1t0, 0, 0, 0);
        s1t0 = __builtin_amdgcn_mfma_f32_16x16x32_bf16(ka11, qb1, s1t0, 0, 0, 0);
        f32x4 s0t1 = (f32x4)0.0f, s1t1 = (f32x4)0.0f;
        s0t1 = __builtin_amdgcn_mfma_f32_16x16x32_bf16(ka00, qc0, s0t1, 0, 0, 0);
        s0t1 = __builtin_amdgcn_mfma_f32_16x16x32_bf16(ka01, qc1, s0t1, 0, 0, 0);
        s1t1 = __builtin_amdgcn_mfma_f32_16x16x32_bf16(ka10, qc0, s1t1, 0, 0, 0);
        s1t1 = __builtin_amdgcn_mfma_f32_16x16x32_bf16(ka11, qc1, s1t1, 0, 0, 0);

        // ---- per-tile softmax + PV ----
        #pragma unroll
        for (int t = 0; t < 2; ++t) {
            const f32x4 s0 = t ? s0t1 : s0t0;
            const f32x4 s1 = t ? s1t1 : s1t0;
            const unsigned int mw32 = t ? mw1[i] : mw0[i];
            float& m_run = t ? m1 : m0;
            float& l_run = t ? l1 : l0;
            f32x4* o = t ? o1 : o0;

            float sv[8];
            #pragma unroll
            for (int r = 0; r < 4; ++r) {
                sv[r]     = ((mw32 >> (g * 4 + r)) & 1u)      ? -INFINITY : s0[r] * scale;
                sv[4 + r] = ((mw32 >> (16 + g * 4 + r)) & 1u) ? -INFINITY : s1[r] * scale;
            }

            float mx = fmaxf(fmaxf(fmaxf(sv[0], sv[1]), fmaxf(sv[2], sv[3])),
                             fmaxf(fmaxf(sv[4], sv[5]), fmaxf(sv[6], sv[7])));
            mx = fmaxf(mx, __shfl_xor(mx, 16));
            mx = fmaxf(mx, __shfl_xor(mx, 32));

            if (!__all(mx <= m_run + 8.0f)) {
                float mn = fmaxf(m_run, mx);
                float cf = (m_run == mn) ? 1.0f : exp2f((m_run - mn) * LOG2E);
                float cfq[4];
                #pragma unroll
                for (int r = 0; r < 4; ++r)
                    cfq[r] = __shfl(cf, (lane & 48) | (g * 4 + r));
                #pragma unroll
                for (int n = 0; n < 4; ++n)
                    #pragma unroll
                    for (int r = 0; r < 4; ++r) o[n][r] *= cfq[r];
                l_run *= cf;
                m_run = mn;
            }

            const float mb = m_run * LOG2E;
            float p[8];
            #pragma unroll
            for (int j = 0; j < 8; ++j)
                p[j] = (sv[j] <= -1e37f) ? 0.0f : exp2f(sv[j] * LOG2E - mb);
            float rs = ((p[0] + p[1]) + (p[2] + p[3])) + ((p[4] + p[5]) + (p[6] + p[7]));
            rs += __shfl_xor(rs, 16);
            rs += __shfl_xor(rs, 32);
            l_run += rs;

            bf16x4 p0v, p1v;
            #pragma unroll
            for (int r = 0; r < 4; ++r) { p0v[r] = f2bf(p[r]); p1v[r] = f2bf(p[4 + r]); }
            *(bf16x4*)&P_lds[w][t][g >> 1][c][(g & 1) * 4]       = p0v;
            *(bf16x4*)&P_lds[w][t][2 + (g >> 1)][c][(g & 1) * 4] = p1v;
            bf16x8 pa = *(bf16x8*)&P_lds[w][t][g][c][0];
            #pragma unroll
            for (int n = 0; n < 4; ++n)
                o[n] = __builtin_amdgcn_mfma_f32_16x16x32_bf16(pa, vb[n], o[n], 0, 0, 0);
        }
    }

    // ---- merge: tile0 then tile1 through the same 32KB buffer ----
    const int row  = tid >> 5;
    const int col0 = (tid & 31) * 2;
    float* Ob0 = out + (size_t)(b * SEQ + qbase + row) * HEAD;
    float* Ob1 = out + (size_t)(b * SEQ + qbase + 16 + row) * HEAD;

    #pragma unroll
    for (int t = 0; t < 2; ++t) {
        __syncthreads();   // P reads done (t=0) / previous merge reads done (t=1)
        const f32x4* o = t ? o1 : o0;
        #pragma unroll
        for (int n = 0; n < 4; ++n)
            #pragma unroll
            for (int r = 0; r < 4; ++r)
                O_lds[w][g * 4 + r][n * 16 + c] = o[n][r];
        if (lane < 16) {
            M_lds[w][lane] = t ? m1 : m0;
            L_lds[w][lane] = t ? l1 : l0;
        }
        __syncthreads();

        float M = -INFINITY;
        #pragma unroll
        for (int i = 0; i < 8; ++i) M = fmaxf(M, M_lds[i][row]);
        float L = 0.0f, a0 = 0.0f, a1 = 0.0f;
        #pragma unroll
        for (int i = 0; i < 8; ++i) {
            float wgt = exp2f((M_lds[i][row] - M) * LOG2E);
            L  += L_lds[i][row] * wgt;
            a0 += O_lds[i][row][col0]     * wgt;
            a1 += O_lds[i][row][col0 + 1] * wgt;
        }
        float inv = 1.0f / L;
        float* Ob = t ? Ob1 : Ob0;
        Ob[col0]     = a0 * inv;
        Ob[col0 + 1] = a1 * inv;
    }
}

extern "C" void kernel_launch(void* const* d_in, const int* in_sizes, int n_in,
                              void* d_out, int out_size, void* d_ws, size_t ws_size,
                              hipStream_t stream)
{
    // setup_inputs order: key_input, query_input, value_input, mask, Wq, Wk, Wv
    const float* key_in   = (const float*)d_in[0];
    const float* query_in = (const float*)d_in[1];
    const float* value_in = (const float*)d_in[2];
    const void*  mask     = d_in[3];
    const float* Wq = (const float*)d_in[4];
    const float* Wk = (const float*)d_in[5];
    const float* Wv = (const float*)d_in[6];

    char* ws = (char*)d_ws;
    short* Qw  = (short*)ws;                            // 1 MB
    short* Kw  = Qw + (size_t)BATCH * SEQ * HEAD;       // 1 MB
    short* Vtw = Kw + (size_t)BATCH * SEQ * HEAD;       // 1 MB
    unsigned long long* packed =
        (unsigned long long*)(ws + (size_t)3 * BATCH * SEQ * HEAD * sizeof(short));  // 2 MB
    short* Wt  = (short*)((char*)packed + (size_t)NCHUNK * 8);   // 384 KB
    int* mflag = (int*)((char*)Wt + (size_t)3 * HEAD * DIM * sizeof(short));

    wconv_detect_kernel<<<dim3(16, 3), 256, 0, stream>>>(
        Wq, Wk, Wv, Wt, (const unsigned int*)mask, mflag);

    prep_kernel<<<2048, 256, 0, stream>>>(
        query_in, key_in, value_in, Wt, mask, mflag, packed, Qw, Kw, Vtw);

    attn_kernel<<<256, 512, 0, stream>>>(
        Qw, Kw, Vtw, (const unsigned int*)packed, (float*)d_out);
}

// Round 17
// 57.544 us; speedup vs baseline: 1.4427x; 1.0780x over previous
//
#include <hip/hip_runtime.h>
#include <hip/hip_bf16.h>
#include <math.h>

#define BATCH 4
#define SEQ   2048
#define DIM   1024
#define HEAD  64
#define NCHUNK ((BATCH * SEQ * SEQ) / 64)   // 262144 64-bool chunks

typedef __attribute__((ext_vector_type(8))) short bf16x8;
typedef __attribute__((ext_vector_type(4))) short bf16x4;
typedef __attribute__((ext_vector_type(4))) float f32x4;

static __device__ __forceinline__ short f2bf(float f) {
    __hip_bfloat16 h = __float2bfloat16(f);     // RNE
    return *reinterpret_cast<short*>(&h);
}

// ---------------------------------------------------------------------------
// Prelude: W[1024][64] f32 -> frag-major Wt2[which][k/32][64][32] bf16, so a
// proj wave's B-frag load (n,c,g lanes) is one contiguous 1KB segment.
// Plus mask dtype detect (int32 bools are {0,1}; byte-bools read as u32
// exceed 1 w.p. 7/8 per word).
// ---------------------------------------------------------------------------
__global__ __launch_bounds__(256) void wconv_detect_kernel(
    const float* __restrict__ Wq, const float* __restrict__ Wk, const float* __restrict__ Wv,
    short* __restrict__ Wt, const unsigned int* __restrict__ mask_u32,
    int* __restrict__ mflag)
{
    const int which = blockIdx.y;
    const float* __restrict__ W = (which == 0) ? Wq : (which == 1) ? Wk : Wv;
    short* __restrict__ Wtw = Wt + (size_t)which * HEAD * DIM;

    const int h  = threadIdx.x & 63;
    const int k0 = blockIdx.x * 64 + (threadIdx.x >> 6) * 16;
    #pragma unroll
    for (int j = 0; j < 16; ++j) {
        int k = k0 + j;
        Wtw[((size_t)(k >> 5) * 64 + h) * 32 + (k & 31)] =
            f2bf(W[(size_t)k * HEAD + h]);
    }

    if (blockIdx.x == 0 && blockIdx.y == 0 && threadIdx.x < 64) {
        int lane = threadIdx.x;
        bool weird = false;
        for (int i = lane; i < 1024; i += 64) weird |= (mask_u32[i] > 1u);
        unsigned long long b = __ballot(weird);
        if (lane == 0) *mflag = (b != 0ull) ? 1 : 0;
    }
}

// ---------------------------------------------------------------------------
// Fused prep v2: grid 1280 x 256.
//   blocks [0,512):   mask bit-pack (67 MB stream)
//   blocks [512,1280): projection, M=32 variant: 32 rows x 64 cols per block,
//                      4 waves split-K 256; each W fragment feeds TWO 16-row
//                      A-operands -> per-output load count drops 48->32 and
//                      W L2 re-read traffic halves (196->98 MB). 32 KB LDS
//                      f32 merge.
// ---------------------------------------------------------------------------
__global__ __launch_bounds__(256, 4) void prep_kernel(
    const float* __restrict__ Xq, const float* __restrict__ Xk, const float* __restrict__ Xv,
    const short* __restrict__ Wt, const void* __restrict__ mask,
    const int* __restrict__ mflag, unsigned long long* __restrict__ packed,
    short* __restrict__ Q, short* __restrict__ K, short* __restrict__ Vt)
{
    const int bx  = blockIdx.x;
    const int tid = threadIdx.x;
    const int lane = tid & 63;
    const int w    = tid >> 6;

    if (bx < 512) {
        // ------------------------- mask pack -------------------------
        const int gw = bx * 4 + w;                // 0..2047
        const int c0 = gw * 128;
        const int useByte = *mflag;
        if (useByte) {
            const unsigned char* mb = (const unsigned char*)mask;
            for (int i = 0; i < 8; ++i) {
                unsigned char v[16];
                #pragma unroll
                for (int j = 0; j < 16; ++j)
                    v[j] = mb[(size_t)(c0 + i * 16 + j) * 64 + lane];
                #pragma unroll
                for (int j = 0; j < 16; ++j) {
                    unsigned long long bb = __ballot(v[j] != 0);
                    if (lane == 0) packed[c0 + i * 16 + j] = bb;
                }
            }
        } else {
            const unsigned int* mw = (const unsigned int*)mask;
            for (int i = 0; i < 8; ++i) {
                unsigned int v[16];
                #pragma unroll
                for (int j = 0; j < 16; ++j)
                    v[j] = mw[(size_t)(c0 + i * 16 + j) * 64 + lane];
                #pragma unroll
                for (int j = 0; j < 16; ++j) {
                    unsigned long long bb = __ballot(v[j] != 0);
                    if (lane == 0) packed[c0 + i * 16 + j] = bb;
                }
            }
        }
        return;
    }

    // ------------------- projection (proj5-M32 core) -------------------
    __shared__ float O_lds[4][32][64];          // [wave][row][col] partials, 32KB

    const int pi    = bx - 512;                 // 0..767
    const int which = pi >> 8;                  // 0:Q 1:K 2:V (256 blocks each)
    const int row0  = (pi & 255) * 32;          // global row (b*S+s)
    const float* __restrict__ X = (which == 0) ? Xq : (which == 1) ? Xk : Xv;
    const short* __restrict__ Wtw = Wt + (size_t)which * HEAD * DIM;

    const int g = lane >> 4;
    const int c = lane & 15;

    const float* __restrict__ Xp0 = X + (size_t)(row0 + c) * DIM + w * 256 + g * 8;
    const float* __restrict__ Xp1 = Xp0 + (size_t)16 * DIM;
    const short* __restrict__ Wp  = Wtw + (size_t)(w * 8) * 2048 + c * 32 + g * 8;

    f32x4 acc0[4], acc1[4];
    #pragma unroll
    for (int n = 0; n < 4; ++n) { acc0[n] = (f32x4)0.0f; acc1[n] = (f32x4)0.0f; }

    #pragma unroll
    for (int half = 0; half < 2; ++half) {
        f32x4 xa0[4], xb0[4], xa1[4], xb1[4];
        #pragma unroll
        for (int s = 0; s < 4; ++s) {
            xa0[s] = *(const f32x4*)(Xp0 + half * 128 + s * 32);
            xb0[s] = *(const f32x4*)(Xp0 + half * 128 + s * 32 + 4);
            xa1[s] = *(const f32x4*)(Xp1 + half * 128 + s * 32);
            xb1[s] = *(const f32x4*)(Xp1 + half * 128 + s * 32 + 4);
        }
        bf16x8 wf[16];
        #pragma unroll
        for (int s = 0; s < 4; ++s)
            #pragma unroll
            for (int n = 0; n < 4; ++n)
                wf[s * 4 + n] = *(const bf16x8*)(Wp + (size_t)(half * 4 + s) * 2048
                                                 + n * 512);
        #pragma unroll
        for (int s = 0; s < 4; ++s) {
            bf16x8 a0, a1;
            a0[0]=f2bf(xa0[s][0]); a0[1]=f2bf(xa0[s][1]); a0[2]=f2bf(xa0[s][2]); a0[3]=f2bf(xa0[s][3]);
            a0[4]=f2bf(xb0[s][0]); a0[5]=f2bf(xb0[s][1]); a0[6]=f2bf(xb0[s][2]); a0[7]=f2bf(xb0[s][3]);
            a1[0]=f2bf(xa1[s][0]); a1[1]=f2bf(xa1[s][1]); a1[2]=f2bf(xa1[s][2]); a1[3]=f2bf(xa1[s][3]);
            a1[4]=f2bf(xb1[s][0]); a1[5]=f2bf(xb1[s][1]); a1[6]=f2bf(xb1[s][2]); a1[7]=f2bf(xb1[s][3]);
            #pragma unroll
            for (int n = 0; n < 4; ++n) {
                acc0[n] = __builtin_amdgcn_mfma_f32_16x16x32_bf16(a0, wf[s * 4 + n],
                                                                  acc0[n], 0, 0, 0);
                acc1[n] = __builtin_amdgcn_mfma_f32_16x16x32_bf16(a1, wf[s * 4 + n],
                                                                  acc1[n], 0, 0, 0);
            }
        }
    }

    // publish partials: C/D layout col = lane&15 (W col), row = g*4+reg (X row)
    #pragma unroll
    for (int n = 0; n < 4; ++n)
        #pragma unroll
        for (int r = 0; r < 4; ++r) {
            O_lds[w][g * 4 + r][n * 16 + c]      = acc0[n][r];
            O_lds[w][16 + g * 4 + r][n * 16 + c] = acc1[n][r];
        }
    __syncthreads();

    if (which < 2) {
        short* dst = (which == 0) ? Q : K;
        const int trow = tid >> 3, c8 = (tid & 7) * 8;   // 32 rows x 8 cols
        f32x4 sA = *(const f32x4*)&O_lds[0][trow][c8];
        f32x4 sB = *(const f32x4*)&O_lds[0][trow][c8 + 4];
        #pragma unroll
        for (int i = 1; i < 4; ++i) {
            f32x4 tA = *(const f32x4*)&O_lds[i][trow][c8];
            f32x4 tB = *(const f32x4*)&O_lds[i][trow][c8 + 4];
            #pragma unroll
            for (int j = 0; j < 4; ++j) { sA[j] += tA[j]; sB[j] += tB[j]; }
        }
        bf16x8 pk;
        #pragma unroll
        for (int j = 0; j < 4; ++j) { pk[j] = f2bf(sA[j]); pk[4 + j] = f2bf(sB[j]); }
        *(bf16x8*)&dst[(size_t)(row0 + trow) * HEAD + c8] = pk;
    } else {
        // Vt[b][h][s]: thread owns one h, 8 consecutive s
        const int h = tid & 63, r8 = (tid >> 6) * 8;
        const int b = row0 >> 11, sb = row0 & (SEQ - 1);
        bf16x8 pk;
        #pragma unroll
        for (int j = 0; j < 8; ++j) {
            float v = O_lds[0][r8 + j][h] + O_lds[1][r8 + j][h]
                    + O_lds[2][r8 + j][h] + O_lds[3][r8 + j][h];
            pk[j] = f2bf(v);
        }
        *(bf16x8*)&Vt[((size_t)(b * HEAD + h)) * SEQ + sb + r8] = pk;
    }
}

// ---------------------------------------------------------------------------
// Flash attention v5 (R16, ~9 us): 256 blocks x 512 threads. Block = (batch,
// 32 q-rows): bi&3 = batch -> per-XCD L2-resident K/V/Q/packed. Wave w owns
// keys [w*256,(w+1)*256); K/V frags feed two q-tiles. Swapped QK^T, in-lane
// softmax, bit-mask words, defer-max, P->LDS->PV.
// ---------------------------------------------------------------------------
__global__ __launch_bounds__(512, 2) void attn_kernel(
    const short* __restrict__ Q, const short* __restrict__ K, const short* __restrict__ Vt,
    const unsigned int* __restrict__ packed, float* __restrict__ out)
{
    const int bi    = blockIdx.x;
    const int b     = bi & 3;            // XCD-friendly: batch -> XCDs {b, b+4}
    const int qbase = (bi >> 2) * 32;
    const int tid  = threadIdx.x;
    const int lane = tid & 63;
    const int w    = tid >> 6;          // wave 0..7 = key segment
    const int g    = lane >> 4;
    const int c    = lane & 15;

    const short* Qb = Q  + (size_t)(b * SEQ + qbase) * HEAD;
    const short* Kb = K  + (size_t)b * SEQ * HEAD;
    const short* Vb = Vt + (size_t)b * HEAD * SEQ;

    // LDS: P (loop phase, 16KB: 2 tiles) aliases O (merge phase, 32KB).
    __shared__ __align__(16) unsigned char smem[32768 + 1024];
    short (*P_lds)[2][4][16][8] = (short (*)[2][4][16][8])smem; // [wave][tile][kgrp][q][8]
    float (*O_lds)[16][64]      = (float (*)[16][64])smem;      // [wave][q][h]
    float (*M_lds)[16] = (float (*)[16])(smem + 32768);         // [wave][q]
    float (*L_lds)[16] = (float (*)[16])(smem + 32768 + 512);

    // per-lane mask bits: tile0 q = qbase+c, tile1 q = qbase+16+c
    const unsigned int* pw0 = packed + (size_t)(b * SEQ + qbase + c) * 64 + w * 8;
    unsigned int mw0[8], mw1[8];
    #pragma unroll
    for (int i = 0; i < 8; ++i) { mw0[i] = pw0[i]; mw1[i] = pw0[16 * 64 + i]; }

    // Q as B-operand fragments for both tiles
    bf16x8 qb0 = *(const bf16x8*)&Qb[c * HEAD + g * 8];
    bf16x8 qb1 = *(const bf16x8*)&Qb[c * HEAD + 32 + g * 8];
    bf16x8 qc0 = *(const bf16x8*)&Qb[(16 + c) * HEAD + g * 8];
    bf16x8 qc1 = *(const bf16x8*)&Qb[(16 + c) * HEAD + 32 + g * 8];

    float m0 = -INFINITY, l0 = 0.0f, m1 = -INFINITY, l1 = 0.0f;
    f32x4 o0[4], o1[4];
    #pragma unroll
    for (int n = 0; n < 4; ++n) { o0[n] = (f32x4)0.0f; o1[n] = (f32x4)0.0f; }

    const float scale = 0.125f;                    // HEAD^-0.5
    const float LOG2E = 1.44269504088896340736f;

    for (int i = 0; i < 8; ++i) {
        const int kt = w * 8 + i;                  // key tile of 32
        const short* Kt = Kb + (size_t)kt * 32 * HEAD;

        // V^T B-fragments (shared by both q-tiles)
        bf16x8 vb[4];
        #pragma unroll
        for (int n = 0; n < 4; ++n)
            vb[n] = *(const bf16x8*)&Vb[(size_t)(n * 16 + c) * SEQ + kt * 32 + g * 8];

        // K as A-operand (shared by both q-tiles)
        bf16x8 ka00 = *(const bf16x8*)&Kt[c * HEAD + g * 8];
        bf16x8 ka01 = *(const bf16x8*)&Kt[c * HEAD + 32 + g * 8];
        bf16x8 ka10 = *(const bf16x8*)&Kt[(16 + c) * HEAD + g * 8];
        bf16x8 ka11 = *(const bf16x8*)&Kt[(16 + c) * HEAD + 32 + g * 8];

        // ---- both tiles' QK^T (K frags reused) ----
        f32x4 s0t0 = (f32x4)0.0f, s1t0 = (f32x4)0.0f;
        s0t0 = __builtin_amdgcn_mfma_f32_16x16x32_bf16(ka00, qb0, s0t0, 0, 0, 0);
        s0t0 = __builtin_amdgcn_mfma_f32_16x16x32_bf16(ka01, qb1, s0t0, 0, 0, 0);
        s1t0 = __builtin_amdgcn_mfma_f32_16x16x32_bf16(ka10, qb0, s1t0, 0, 0, 0);
        s1t0 = __builtin_amdgcn_mfma_f32_16x16x32_bf16(ka11, qb1, s1t0, 0, 0, 0);
        f32x4 s0t1 = (f32x4)0.0f, s1t1 = (f32x4)0.0f;
        s0t1 = __builtin_amdgcn_mfma_f32_16x16x32_bf16(ka00, qc0, s0t1, 0, 0, 0);
        s0t1 = __builtin_amdgcn_mfma_f32_16x16x32_bf16(ka01, qc1, s0t1, 0, 0, 0);
        s1t1 = __builtin_amdgcn_mfma_f32_16x16x32_bf16(ka10, qc0, s1t1, 0, 0, 0);
        s1t1 = __builtin_amdgcn_mfma_f32_16x16x32_bf16(ka11, qc1, s1t1, 0, 0, 0);

        // ---- per-tile softmax + PV ----
        #pragma unroll
        for (int t = 0; t < 2; ++t) {
            const f32x4 s0 = t ? s0t1 : s0t0;
            const f32x4 s1 = t ? s1t1 : s1t0;
            const unsigned int mw32 = t ? mw1[i] : mw0[i];
            float& m_run = t ? m1 : m0;
            float& l_run = t ? l1 : l0;
            f32x4* o = t ? o1 : o0;

            float sv[8];
            #pragma unroll
            for (int r = 0; r < 4; ++r) {
                sv[r]     = ((mw32 >> (g * 4 + r)) & 1u)      ? -INFINITY : s0[r] * scale;
                sv[4 + r] = ((mw32 >> (16 + g * 4 + r)) & 1u) ? -INFINITY : s1[r] * scale;
            }

            float mx = fmaxf(fmaxf(fmaxf(sv[0], sv[1]), fmaxf(sv[2], sv[3])),
                             fmaxf(fmaxf(sv[4], sv[5]), fmaxf(sv[6], sv[7])));
            mx = fmaxf(mx, __shfl_xor(mx, 16));
            mx = fmaxf(mx, __shfl_xor(mx, 32));

            if (!__all(mx <= m_run + 8.0f)) {
                float mn = fmaxf(m_run, mx);
                float cf = (m_run == mn) ? 1.0f : exp2f((m_run - mn) * LOG2E);
                float cfq[4];
                #pragma unroll
                for (int r = 0; r < 4; ++r)
                    cfq[r] = __shfl(cf, (lane & 48) | (g * 4 + r));
                #pragma unroll
                for (int n = 0; n < 4; ++n)
                    #pragma unroll
                    for (int r = 0; r < 4; ++r) o[n][r] *= cfq[r];
                l_run *= cf;
                m_run = mn;
            }

            const float mb = m_run * LOG2E;
            float p[8];
            #pragma unroll
            for (int j = 0; j < 8; ++j)
                p[j] = (sv[j] <= -1e37f) ? 0.0f : exp2f(sv[j] * LOG2E - mb);
            float rs = ((p[0] + p[1]) + (p[2] + p[3])) + ((p[4] + p[5]) + (p[6] + p[7]));
            rs += __shfl_xor(rs, 16);
            rs += __shfl_xor(rs, 32);
            l_run += rs;

            bf16x4 p0v, p1v;
            #pragma unroll
            for (int r = 0; r < 4; ++r) { p0v[r] = f2bf(p[r]); p1v[r] = f2bf(p[4 + r]); }
            *(bf16x4*)&P_lds[w][t][g >> 1][c][(g & 1) * 4]       = p0v;
            *(bf16x4*)&P_lds[w][t][2 + (g >> 1)][c][(g & 1) * 4] = p1v;
            bf16x8 pa = *(bf16x8*)&P_lds[w][t][g][c][0];
            #pragma unroll
            for (int n = 0; n < 4; ++n)
                o[n] = __builtin_amdgcn_mfma_f32_16x16x32_bf16(pa, vb[n], o[n], 0, 0, 0);
        }
    }

    // ---- merge: tile0 then tile1 through the same 32KB buffer ----
    const int row  = tid >> 5;
    const int col0 = (tid & 31) * 2;
    float* Ob0 = out + (size_t)(b * SEQ + qbase + row) * HEAD;
    float* Ob1 = out + (size_t)(b * SEQ + qbase + 16 + row) * HEAD;

    #pragma unroll
    for (int t = 0; t < 2; ++t) {
        __syncthreads();   // P reads done (t=0) / previous merge reads done (t=1)
        const f32x4* o = t ? o1 : o0;
        #pragma unroll
        for (int n = 0; n < 4; ++n)
            #pragma unroll
            for (int r = 0; r < 4; ++r)
                O_lds[w][g * 4 + r][n * 16 + c] = o[n][r];
        if (lane < 16) {
            M_lds[w][lane] = t ? m1 : m0;
            L_lds[w][lane] = t ? l1 : l0;
        }
        __syncthreads();

        float M = -INFINITY;
        #pragma unroll
        for (int i = 0; i < 8; ++i) M = fmaxf(M, M_lds[i][row]);
        float L = 0.0f, a0 = 0.0f, a1 = 0.0f;
        #pragma unroll
        for (int i = 0; i < 8; ++i) {
            float wgt = exp2f((M_lds[i][row] - M) * LOG2E);
            L  += L_lds[i][row] * wgt;
            a0 += O_lds[i][row][col0]     * wgt;
            a1 += O_lds[i][row][col0 + 1] * wgt;
        }
        float inv = 1.0f / L;
        float* Ob = t ? Ob1 : Ob0;
        Ob[col0]     = a0 * inv;
        Ob[col0 + 1] = a1 * inv;
    }
}

extern "C" void kernel_launch(void* const* d_in, const int* in_sizes, int n_in,
                              void* d_out, int out_size, void* d_ws, size_t ws_size,
                              hipStream_t stream)
{
    // setup_inputs order: key_input, query_input, value_input, mask, Wq, Wk, Wv
    const float* key_in   = (const float*)d_in[0];
    const float* query_in = (const float*)d_in[1];
    const float* value_in = (const float*)d_in[2];
    const void*  mask     = d_in[3];
    const float* Wq = (const float*)d_in[4];
    const float* Wk = (const float*)d_in[5];
    const float* Wv = (const float*)d_in[6];

    char* ws = (char*)d_ws;
    short* Qw  = (short*)ws;                            // 1 MB
    short* Kw  = Qw + (size_t)BATCH * SEQ * HEAD;       // 1 MB
    short* Vtw = Kw + (size_t)BATCH * SEQ * HEAD;       // 1 MB
    unsigned long long* packed =
        (unsigned long long*)(ws + (size_t)3 * BATCH * SEQ * HEAD * sizeof(short));  // 2 MB
    short* Wt  = (short*)((char*)packed + (size_t)NCHUNK * 8);   // 384 KB
    int* mflag = (int*)((char*)Wt + (size_t)3 * HEAD * DIM * sizeof(short));

    wconv_detect_kernel<<<dim3(16, 3), 256, 0, stream>>>(
        Wq, Wk, Wv, Wt, (const unsigned int*)mask, mflag);

    prep_kernel<<<1280, 256, 0, stream>>>(
        query_in, key_in, value_in, Wt, mask, mflag, packed, Qw, Kw, Vtw);

    attn_kernel<<<256, 512, 0, stream>>>(
        Qw, Kw, Vtw, (const unsigned int*)packed, (float*)d_out);
}